// Round 10
// baseline (438.813 us; speedup 1.0000x reference)
//
#include <hip/hip_runtime.h>
#include <hip/hip_bf16.h>

#define N_FEAT 128
#define HID 16
#define NCLS 10
#define NGRAPH 1024
#define SHIFT 7            // 128 nodes per coarse bin
#define NBMAX 1024         // supports n <= 131072
#define CAP 9216           // LDS staging entries in k_place (36 KB, +11 sigma)
#define CH 8192            // edges per binning block
#define EPB2 (CH / 512)    // edges per thread in k_binhist/k_binplace (512 thr)
#define GC_NODES 64        // nodes per gather block (4 threads/node, 256 thr)
#define GCAP2 5120         // LDS col staging in k_gc (20 KB, ~16 sigma at mean 4096)
#define CPAD 16            // cursor/binCnt padding: one 64B line per bin

__device__ __forceinline__ float u2f(unsigned int u) {
    union { unsigned int u; float f; } c; c.u = u; return c.f;
}
__device__ __forceinline__ float bf2f(__hip_bfloat16 b) {
    return __bfloat162float(b);
}
__device__ __forceinline__ unsigned short f2us(float f) {
    union { __hip_bfloat16 b; unsigned short u; } c;
    c.b = __float2bfloat16(f);
    return c.u;
}
__device__ __forceinline__ float ldw(const void* __restrict__ p, int i, int isbf) {
    return isbf ? bf2f(((const __hip_bfloat16*)p)[i]) : ((const float*)p)[i];
}
// unpack 8 bf16 packed in a uint4 into f[0..7]
__device__ __forceinline__ void unp8(uint4 v, float* f) {
    f[0] = u2f(v.x << 16); f[1] = u2f(v.x & 0xffff0000u);
    f[2] = u2f(v.y << 16); f[3] = u2f(v.y & 0xffff0000u);
    f[4] = u2f(v.z << 16); f[5] = u2f(v.z & 0xffff0000u);
    f[6] = u2f(v.w << 16); f[7] = u2f(v.w & 0xffff0000u);
}
// accumulate 8 bf16 packed in a uint4 into a8[0..7]
__device__ __forceinline__ void acc8(uint4 v, float* a8) {
    a8[0] += u2f(v.x << 16); a8[1] += u2f(v.x & 0xffff0000u);
    a8[2] += u2f(v.y << 16); a8[3] += u2f(v.y & 0xffff0000u);
    a8[4] += u2f(v.z << 16); a8[5] += u2f(v.z & 0xffff0000u);
    a8[6] += u2f(v.w << 16); a8[7] += u2f(v.w & 0xffff0000u);
}

// ---------------------------------------------------------------------------
// K0: runtime dtype probes + padded binCnt zero-init.
__global__ void k_detect(const int* __restrict__ ei,
                         const unsigned int* __restrict__ xw,
                         int* __restrict__ flags,
                         int* __restrict__ binCnt, int nbins) {
    int t = threadIdx.x;
    for (int b = t; b < nbins; b += 1024) binCnt[(size_t)b * CPAD] = 0;
    if (t == 0) {
        int nz = 0;
        for (int i = 1; i < 256; i += 2) nz |= ei[i];
        flags[0] = (nz == 0) ? 1 : 0;
        int cnt = 0;
        for (int i = 0; i < 64; i++) {
            unsigned int ef = xw[i] & 0x7F80u;
            if (ef >= 0x3C00u && ef <= 0x4080u) cnt++;
        }
        flags[1] = (cnt >= 32) ? 1 : 0;
    }
}

// ---------------------------------------------------------------------------
// K1: h0[i] = emb[argmax(x[i,:])]. 2 nodes per wave, float4/uint2 loads.
__global__ void k_argmax_embed(const void* __restrict__ x,
                               const void* __restrict__ emb,
                               const int* __restrict__ flags,
                               unsigned short* __restrict__ h, int n) {
    int wave = (int)((blockIdx.x * (unsigned)blockDim.x + threadIdx.x) >> 6);
    int lane = threadIdx.x & 63;
    int half = lane >> 5;
    int l = lane & 31;
    int node = wave * 2 + half;
    if (node >= n) return;
    int isbf = flags[1];
    float v[4];
    if (isbf) {
        uint2 u = ((const uint2*)((const __hip_bfloat16*)x + (size_t)node * N_FEAT))[l];
        v[0] = u2f(u.x << 16); v[1] = u2f(u.x & 0xffff0000u);
        v[2] = u2f(u.y << 16); v[3] = u2f(u.y & 0xffff0000u);
    } else {
        float4 u = ((const float4*)((const float*)x + (size_t)node * N_FEAT))[l];
        v[0] = u.x; v[1] = u.y; v[2] = u.z; v[3] = u.w;
    }
    float bv = v[0]; int bi = 4 * l;
    #pragma unroll
    for (int k = 1; k < 4; k++)
        if (v[k] > bv) { bv = v[k]; bi = 4 * l + k; }
    #pragma unroll
    for (int off = 1; off < 32; off <<= 1) {
        float ov = __shfl_xor(bv, off);
        int   oi = __shfl_xor(bi, off);
        if (ov > bv || (ov == bv && oi < bi)) { bv = ov; bi = oi; }
    }
    if (l < HID) {
        unsigned short us;
        if (isbf) us = ((const unsigned short*)emb)[bi * HID + l];  // exact copy
        else      us = f2us(((const float*)emb)[bi * HID + l]);
        h[(size_t)node * HID + l] = us;
    }
}

// ---------------------------------------------------------------------------
// K2a: per-block LDS bin histogram -> padded global atomic accumulate.
__global__ __launch_bounds__(512) void k_binhist(
        const int* __restrict__ ei, const int* __restrict__ flags,
        int* __restrict__ binCnt, int e, int nbins) {
    __shared__ int lh[NBMAX];
    int t = threadIdx.x;
    for (int b = t; b < nbins; b += 512) lh[b] = 0;
    __syncthreads();
    int base = blockIdx.x * CH;
    int sh = flags[0];
    for (int j = 0; j < EPB2; j++) {
        int i = base + j * 512 + t;
        if (i < e) {
            int d = ei[((size_t)(e + i)) << sh];
            atomicAdd(&lh[d >> SHIFT], 1);
        }
    }
    __syncthreads();
    for (int b = t; b < nbins; b += 512) {
        int c = lh[b];
        if (c) atomicAdd(&binCnt[(size_t)b * CPAD], c);
    }
}

// K2c: exclusive scan of padded binCnt -> binStart; init padded cursor.
__global__ void k_scanbins(const int* __restrict__ binCnt,
                           int* __restrict__ binStart,
                           int* __restrict__ cursor, int nbins, int e) {
    __shared__ int ls[1024];
    int t = threadIdx.x;
    int v = (t < nbins) ? binCnt[(size_t)t * CPAD] : 0;
    ls[t] = v;
    __syncthreads();
    #pragma unroll
    for (int off = 1; off < 1024; off <<= 1) {
        int w = (t >= off) ? ls[t - off] : 0;
        __syncthreads();
        ls[t] += w;
        __syncthreads();
    }
    if (t < nbins) {
        int s = ls[t] - v;
        binStart[t] = s;
        cursor[(size_t)t * CPAD] = s;
    }
    if (t == 0) binStart[nbins] = e;
}

// K2d: coarse placement, LDS-sorted writes, padded per-bin cursor claims.
// R10: cursor strided to 1 line/bin — R9's 80us was per-line atomic queueing
// (782 blocks x 16 bins/line = 12.5K serialized RMWs/line on 49 lines).
__global__ __launch_bounds__(512) void k_binplace(
        const int* __restrict__ ei, const int* __restrict__ flags,
        int* __restrict__ cursor,
        int* __restrict__ col, int e, int nbins) {
    __shared__ int cnt[NBMAX];
    __shared__ int ldsOff[NBMAX];
    __shared__ int ldsBase[NBMAX];
    __shared__ int ps[512];
    __shared__ int stage[CH];
    __shared__ unsigned short binOf[CH];
    int t = threadIdx.x;
    for (int b = t; b < nbins; b += 512) cnt[b] = 0;
    __syncthreads();
    int base = blockIdx.x * CH;
    int sh = flags[0];
    int myV[EPB2]; short myB[EPB2];
    for (int j = 0; j < EPB2; j++) {
        int i = base + j * 512 + t;
        if (i < e) {
            int s = ei[((size_t)i) << sh];
            int d = ei[((size_t)(e + i)) << sh];
            myV[j] = (s << SHIFT) | (d & ((1 << SHIFT) - 1));
            int b2 = d >> SHIFT;
            myB[j] = (short)b2;
            atomicAdd(&cnt[b2], 1);
        } else myB[j] = -1;
    }
    __syncthreads();
    int c[2]; int lsum = 0;
    int bb = t * 2;
    #pragma unroll
    for (int k = 0; k < 2; k++) {
        int b2 = bb + k;
        c[k] = (b2 < nbins) ? cnt[b2] : 0;
        lsum += c[k];
    }
    ps[t] = lsum;
    __syncthreads();
    #pragma unroll
    for (int off = 1; off < 512; off <<= 1) {
        int w = (t >= off) ? ps[t - off] : 0;
        __syncthreads();
        ps[t] += w;
        __syncthreads();
    }
    int run = ps[t] - lsum;
    #pragma unroll
    for (int k = 0; k < 2; k++) {
        int b2 = bb + k;
        if (b2 < nbins) {
            ldsOff[b2] = run;
            if (c[k] > 0) {
                int g = atomicAdd(&cursor[(size_t)b2 * CPAD], c[k]);
                ldsBase[b2] = g - run;
            }
            cnt[b2] = 0;
        }
        run += c[k];
    }
    __syncthreads();
    for (int j = 0; j < EPB2; j++) {
        if (myB[j] >= 0) {
            int b2 = myB[j];
            int r = atomicAdd(&cnt[b2], 1);
            int p = ldsOff[b2] + r;
            stage[p] = myV[j];
            binOf[p] = (unsigned short)b2;
        }
    }
    __syncthreads();
    int total = e - base;
    if (total > CH) total = CH;
    for (int i = t; i < total; i += 512) {
        int b2 = binOf[i];
        col[ldsBase[b2] + i] = stage[i];
    }
}

// K2e: fine placement + per-node rowStart (36 KB stage, 512 thr — R2/R6 win).
__global__ __launch_bounds__(512) void k_place(
        int* __restrict__ col, const int* __restrict__ binStart,
        int* __restrict__ rowStart, int n, int e) {
    __shared__ int stage[CAP];
    __shared__ int cntN[1 << SHIFT];
    __shared__ int sc[1 << SHIFT];
    __shared__ int rs[1 << SHIFT];
    int b = blockIdx.x;
    int t = threadIdx.x;
    int nb = b << SHIFT;
    int s0 = binStart[b];
    int s1 = binStart[b + 1];
    int cnt = s1 - s0;
    if (t < (1 << SHIFT)) cntN[t] = 0;
    bool st = (cnt <= CAP);
    __syncthreads();
    for (int i = t; i < cnt; i += 512) {
        int v = col[s0 + i];
        if (st) stage[i] = v;
        atomicAdd(&cntN[v & ((1 << SHIFT) - 1)], 1);
    }
    __syncthreads();
    if (t < (1 << SHIFT)) sc[t] = cntN[t];
    __syncthreads();
    #pragma unroll
    for (int off = 1; off < (1 << SHIFT); off <<= 1) {
        int w = 0;
        if (t < (1 << SHIFT) && t >= off) w = sc[t - off];
        __syncthreads();
        if (t < (1 << SHIFT)) sc[t] += w;
        __syncthreads();
    }
    if (t < (1 << SHIFT)) {
        int start = s0 + sc[t] - cntN[t];
        rs[t] = start;
        int node = nb + t;
        if (node < n) rowStart[node] = start;
        cntN[t] = 0;
    }
    __syncthreads();
    for (int i = t; i < cnt; i += 512) {
        int v = st ? stage[i] : col[s0 + i];
        int dl = v & ((1 << SHIFT) - 1);
        int r = atomicAdd(&cntN[dl], 1);
        col[rs[dl] + r] = v >> SHIFT;
    }
}

// ---------------------------------------------------------------------------
// K3: gather+combine, layers 1/2. R7 structure (FROZEN — MSHR-bound floor).
__global__ __launch_bounds__(256) void k_gc(
        const int* __restrict__ col, const int* __restrict__ rowStart,
        const unsigned short* __restrict__ hin,
        const void* __restrict__ Wl, const void* __restrict__ bia,
        const void* __restrict__ Wr, const int* __restrict__ flags,
        unsigned short* __restrict__ hout, int n, int e) {
    __shared__ int ecol[GCAP2];
    __shared__ float wl[HID][HID], wr[HID][HID], bb[HID];
    int t = threadIdx.x;
    int b = blockIdx.x;
    int isbf = flags[1];
    if (t < HID * HID) {
        wl[t >> 4][t & 15] = ldw(Wl, t, isbf);
        wr[t >> 4][t & 15] = ldw(Wr, t, isbf);
    }
    if (t < HID) bb[t] = ldw(bia, t, isbf);
    int nb = b * GC_NODES;
    int s0 = rowStart[nb];
    int s1 = (nb + GC_NODES < n) ? rowStart[nb + GC_NODES] : e;
    int nl = t >> 2;                      // node-local 0..63
    int q  = t & 3;                       // edge-quarter
    int node = nb + nl;
    bool act = (node < n);
    int lo = 0, hi = 0;
    if (act) {
        lo = rowStart[node];
        hi = (node + 1 < n) ? rowStart[node + 1] : e;
    }
    const uint4* h4 = (const uint4*)hin;
    uint4 sv0, sv1;
    if (act && q == 0) {                  // hoist self-row ahead of staging
        sv0 = h4[(size_t)node * 2];
        sv1 = h4[(size_t)node * 2 + 1];
    }
    int cnt = s1 - s0;
    bool st = (cnt <= GCAP2);
    if (st)
        for (int i = t; i < cnt; i += 256)
            ecol[i] = __builtin_nontemporal_load(col + s0 + i);
    __syncthreads();
    if (!act) return;

    float a16[16];
    #pragma unroll
    for (int k = 0; k < 16; k++) a16[k] = 0.0f;
    if (st) {
        int i = lo - s0 + q;
        int end = hi - s0;
        for (; i + 12 < end; i += 16) {
            int e0 = ecol[i], e1 = ecol[i + 4], e2 = ecol[i + 8], e3 = ecol[i + 12];
            uint4 va0 = h4[(size_t)e0 * 2],     vb0 = h4[(size_t)e0 * 2 + 1];
            uint4 va1 = h4[(size_t)e1 * 2],     vb1 = h4[(size_t)e1 * 2 + 1];
            uint4 va2 = h4[(size_t)e2 * 2],     vb2 = h4[(size_t)e2 * 2 + 1];
            uint4 va3 = h4[(size_t)e3 * 2],     vb3 = h4[(size_t)e3 * 2 + 1];
            acc8(va0, a16); acc8(vb0, a16 + 8);
            acc8(va1, a16); acc8(vb1, a16 + 8);
            acc8(va2, a16); acc8(vb2, a16 + 8);
            acc8(va3, a16); acc8(vb3, a16 + 8);
        }
        for (; i < end; i += 4) {
            int s = ecol[i];
            uint4 va = h4[(size_t)s * 2], vb = h4[(size_t)s * 2 + 1];
            acc8(va, a16); acc8(vb, a16 + 8);
        }
    } else {
        int i = lo + q;
        for (; i + 12 < hi; i += 16) {
            int e0 = col[i], e1 = col[i + 4], e2 = col[i + 8], e3 = col[i + 12];
            uint4 va0 = h4[(size_t)e0 * 2],     vb0 = h4[(size_t)e0 * 2 + 1];
            uint4 va1 = h4[(size_t)e1 * 2],     vb1 = h4[(size_t)e1 * 2 + 1];
            uint4 va2 = h4[(size_t)e2 * 2],     vb2 = h4[(size_t)e2 * 2 + 1];
            uint4 va3 = h4[(size_t)e3 * 2],     vb3 = h4[(size_t)e3 * 2 + 1];
            acc8(va0, a16); acc8(vb0, a16 + 8);
            acc8(va1, a16); acc8(vb1, a16 + 8);
            acc8(va2, a16); acc8(vb2, a16 + 8);
            acc8(va3, a16); acc8(vb3, a16 + 8);
        }
        for (; i < hi; i += 4) {
            int s = col[i];
            uint4 va = h4[(size_t)s * 2], vb = h4[(size_t)s * 2 + 1];
            acc8(va, a16); acc8(vb, a16 + 8);
        }
    }
    // q-reduction (q occupies lane bits 0-1)
    #pragma unroll
    for (int k = 0; k < 16; k++) a16[k] += __shfl_xor(a16[k], 1);
    #pragma unroll
    for (int k = 0; k < 16; k++) a16[k] += __shfl_xor(a16[k], 2);
    if (q == 0) {
        float invd = 1.0f / fmaxf((float)(hi - lo), 1.0f);
        #pragma unroll
        for (int k = 0; k < 16; k++) a16[k] *= invd;
        float hb[HID];
        unp8(sv0, hb);
        unp8(sv1, hb + 8);
        float o[HID]; float sq = 0.0f;
        #pragma unroll
        for (int f = 0; f < HID; f++) {
            float acc = bb[f];
            #pragma unroll
            for (int k = 0; k < HID; k++)
                acc += a16[k] * wl[f][k] + hb[k] * wr[f][k];
            o[f] = acc;
            sq += acc * acc;
        }
        float inn = 1.0f / fmaxf(sqrtf(sq), 1e-12f);
        uint4 w0, w1;
        unsigned int* wp0 = (unsigned int*)&w0;
        unsigned int* wp1 = (unsigned int*)&w1;
        #pragma unroll
        for (int v = 0; v < 4; v++) {
            unsigned int l0 = f2us(fmaxf(o[2 * v] * inn, 0.0f));
            unsigned int h0 = f2us(fmaxf(o[2 * v + 1] * inn, 0.0f));
            wp0[v] = l0 | (h0 << 16);
            unsigned int l1 = f2us(fmaxf(o[8 + 2 * v] * inn, 0.0f));
            unsigned int h1 = f2us(fmaxf(o[8 + 2 * v + 1] * inn, 0.0f));
            wp1[v] = l1 | (h1 << 16);
        }
        ((uint4*)hout)[(size_t)node * 2]     = w0;
        ((uint4*)hout)[(size_t)node * 2 + 1] = w1;
    }
}

// K4: same structure, layer 3 (10 outputs, no ReLU, fp32 h3). FROZEN.
__global__ __launch_bounds__(256) void k_gc3(
        const int* __restrict__ col, const int* __restrict__ rowStart,
        const unsigned short* __restrict__ hin,
        const void* __restrict__ Wl, const void* __restrict__ bia,
        const void* __restrict__ Wr, const int* __restrict__ flags,
        float* __restrict__ h3, int n, int e) {
    __shared__ int ecol[GCAP2];
    __shared__ float wl[NCLS][HID], wr[NCLS][HID], bb[NCLS];
    int t = threadIdx.x;
    int b = blockIdx.x;
    int isbf = flags[1];
    if (t < NCLS * HID) {
        wl[t >> 4][t & 15] = ldw(Wl, t, isbf);
        wr[t >> 4][t & 15] = ldw(Wr, t, isbf);
    }
    if (t < NCLS) bb[t] = ldw(bia, t, isbf);
    int nb = b * GC_NODES;
    int s0 = rowStart[nb];
    int s1 = (nb + GC_NODES < n) ? rowStart[nb + GC_NODES] : e;
    int nl = t >> 2;
    int q  = t & 3;
    int node = nb + nl;
    bool act = (node < n);
    int lo = 0, hi = 0;
    if (act) {
        lo = rowStart[node];
        hi = (node + 1 < n) ? rowStart[node + 1] : e;
    }
    const uint4* h4 = (const uint4*)hin;
    uint4 sv0, sv1;
    if (act && q == 0) {
        sv0 = h4[(size_t)node * 2];
        sv1 = h4[(size_t)node * 2 + 1];
    }
    int cnt = s1 - s0;
    bool st = (cnt <= GCAP2);
    if (st)
        for (int i = t; i < cnt; i += 256)
            ecol[i] = __builtin_nontemporal_load(col + s0 + i);
    __syncthreads();
    if (!act) return;

    float a16[16];
    #pragma unroll
    for (int k = 0; k < 16; k++) a16[k] = 0.0f;
    if (st) {
        int i = lo - s0 + q;
        int end = hi - s0;
        for (; i + 12 < end; i += 16) {
            int e0 = ecol[i], e1 = ecol[i + 4], e2 = ecol[i + 8], e3 = ecol[i + 12];
            uint4 va0 = h4[(size_t)e0 * 2],     vb0 = h4[(size_t)e0 * 2 + 1];
            uint4 va1 = h4[(size_t)e1 * 2],     vb1 = h4[(size_t)e1 * 2 + 1];
            uint4 va2 = h4[(size_t)e2 * 2],     vb2 = h4[(size_t)e2 * 2 + 1];
            uint4 va3 = h4[(size_t)e3 * 2],     vb3 = h4[(size_t)e3 * 2 + 1];
            acc8(va0, a16); acc8(vb0, a16 + 8);
            acc8(va1, a16); acc8(vb1, a16 + 8);
            acc8(va2, a16); acc8(vb2, a16 + 8);
            acc8(va3, a16); acc8(vb3, a16 + 8);
        }
        for (; i < end; i += 4) {
            int s = ecol[i];
            uint4 va = h4[(size_t)s * 2], vb = h4[(size_t)s * 2 + 1];
            acc8(va, a16); acc8(vb, a16 + 8);
        }
    } else {
        int i = lo + q;
        for (; i + 12 < hi; i += 16) {
            int e0 = col[i], e1 = col[i + 4], e2 = col[i + 8], e3 = col[i + 12];
            uint4 va0 = h4[(size_t)e0 * 2],     vb0 = h4[(size_t)e0 * 2 + 1];
            uint4 va1 = h4[(size_t)e1 * 2],     vb1 = h4[(size_t)e1 * 2 + 1];
            uint4 va2 = h4[(size_t)e2 * 2],     vb2 = h4[(size_t)e2 * 2 + 1];
            uint4 va3 = h4[(size_t)e3 * 2],     vb3 = h4[(size_t)e3 * 2 + 1];
            acc8(va0, a16); acc8(vb0, a16 + 8);
            acc8(va1, a16); acc8(vb1, a16 + 8);
            acc8(va2, a16); acc8(vb2, a16 + 8);
            acc8(va3, a16); acc8(vb3, a16 + 8);
        }
        for (; i < hi; i += 4) {
            int s = col[i];
            uint4 va = h4[(size_t)s * 2], vb = h4[(size_t)s * 2 + 1];
            acc8(va, a16); acc8(vb, a16 + 8);
        }
    }
    #pragma unroll
    for (int k = 0; k < 16; k++) a16[k] += __shfl_xor(a16[k], 1);
    #pragma unroll
    for (int k = 0; k < 16; k++) a16[k] += __shfl_xor(a16[k], 2);
    if (q == 0) {
        float invd = 1.0f / fmaxf((float)(hi - lo), 1.0f);
        #pragma unroll
        for (int k = 0; k < 16; k++) a16[k] *= invd;
        float hb[HID];
        unp8(sv0, hb);
        unp8(sv1, hb + 8);
        float o[NCLS]; float sq = 0.0f;
        #pragma unroll
        for (int f = 0; f < NCLS; f++) {
            float acc = bb[f];
            #pragma unroll
            for (int k = 0; k < HID; k++)
                acc += a16[k] * wl[f][k] + hb[k] * wr[f][k];
            o[f] = acc;
            sq += acc * acc;
        }
        float inn = 1.0f / fmaxf(sqrtf(sq), 1e-12f);
        float* op = h3 + (size_t)node * NCLS;
        #pragma unroll
        for (int f = 0; f < NCLS; f++) op[f] = o[f] * inn;
    }
}

// ---------------------------------------------------------------------------
// K5: per-graph mean pool (batch sorted -> binary search) + softmax.
__device__ __forceinline__ int lbound(const int* __restrict__ a, int n, int key, int sh) {
    int lo = 0, hi = n;
    while (lo < hi) {
        int mid = (lo + hi) >> 1;
        if (a[((size_t)mid) << sh] < key) lo = mid + 1; else hi = mid;
    }
    return lo;
}

__global__ void k_pool_softmax(const float* __restrict__ h3,
                               const int* __restrict__ batch,
                               const int* __restrict__ flags,
                               void* __restrict__ out, int n) {
    int g = blockIdx.x;
    int lane = threadIdx.x;
    int sh = flags[0];
    int lo = lbound(batch, n, g, sh);
    int hi = lbound(batch, n, g + 1, sh);
    float acc[NCLS];
    #pragma unroll
    for (int c = 0; c < NCLS; c++) acc[c] = 0.0f;
    for (int i = lo + lane; i < hi; i += 64) {
        const float* r = h3 + (size_t)i * NCLS;
        #pragma unroll
        for (int c = 0; c < NCLS; c++) acc[c] += r[c];
    }
    #pragma unroll
    for (int c = 0; c < NCLS; c++) {
        #pragma unroll
        for (int off = 1; off < 64; off <<= 1)
            acc[c] += __shfl_xor(acc[c], off);
    }
    float invc = 1.0f / fmaxf((float)(hi - lo), 1.0f);
    float m = -1e30f;
    #pragma unroll
    for (int c = 0; c < NCLS; c++) { acc[c] *= invc; m = fmaxf(m, acc[c]); }
    float s = 0.0f;
    #pragma unroll
    for (int c = 0; c < NCLS; c++) { acc[c] = expf(acc[c] - m); s += acc[c]; }
    float invs = 1.0f / s;
    if (lane < NCLS) {
        float v = acc[lane] * invs;
        size_t idx = (size_t)g * NCLS + lane;
        if (flags[1]) ((__hip_bfloat16*)out)[idx] = __float2bfloat16(v);
        else          ((float*)out)[idx] = v;
    }
}

// ---------------------------------------------------------------------------
extern "C" void kernel_launch(void* const* d_in, const int* in_sizes, int n_in,
                              void* d_out, int out_size, void* d_ws, size_t ws_size,
                              hipStream_t stream) {
    const void* x   = d_in[0];
    const int*  ei  = (const int*)d_in[1];
    const int*  bat = (const int*)d_in[2];
    const void* emb = d_in[3];
    const void* W1l = d_in[4];  const void* b1 = d_in[5];  const void* W1r = d_in[6];
    const void* W2l = d_in[7];  const void* b2 = d_in[8];  const void* W2r = d_in[9];
    const void* W3l = d_in[10]; const void* b3 = d_in[11]; const void* W3r = d_in[12];

    int n = in_sizes[0] / N_FEAT;
    int e = in_sizes[1] / 2;
    int nbins = (n + (1 << SHIFT) - 1) >> SHIFT;
    int nblk  = (e + CH - 1) / CH;

    // ws: hcur[16n] bf16 | hnext[16n] bf16 | h3[10n] f32 | col[e] |
    //     rowStart[n] | binStart | binCnt(padded) | cursor(padded) | flags
    unsigned short* hcur  = (unsigned short*)d_ws;
    unsigned short* hnext = hcur + (size_t)n * HID;
    float* h3       = (float*)(hnext + (size_t)n * HID);
    int*   col      = (int*)(h3 + (size_t)n * NCLS);
    int*   rowStart = col + e;
    int*   binStart = rowStart + n;
    int*   binCnt   = binStart + (nbins + 1);
    int*   cursor   = binCnt + (size_t)nbins * CPAD;
    int*   flags    = cursor + (size_t)nbins * CPAD;

    int ngridA = (n + 7) / 8;   // argmax: 2 nodes/wave, 4 waves/block
    int ngc = (n + GC_NODES - 1) / GC_NODES;

    // probes + CSR build (cursor-based placement, padded counters)
    k_detect<<<1, 1024, 0, stream>>>(ei, (const unsigned int*)x, flags, binCnt, nbins);
    k_binhist<<<nblk, 512, 0, stream>>>(ei, flags, binCnt, e, nbins);
    k_scanbins<<<1, 1024, 0, stream>>>(binCnt, binStart, cursor, nbins, e);
    k_binplace<<<nblk, 512, 0, stream>>>(ei, flags, cursor, col, e, nbins);
    k_place<<<nbins, 512, 0, stream>>>(col, binStart, rowStart, n, e);

    // initial embedding (bf16 h table)
    k_argmax_embed<<<ngridA, 256, 0, stream>>>(x, emb, flags, hcur, n);

    // 3 gather+combine layers (64-node blocks, LDS-staged col, full-row loads)
    k_gc <<<ngc, 256, 0, stream>>>(col, rowStart, hcur,  W1l, b1, W1r, flags, hnext, n, e);
    k_gc <<<ngc, 256, 0, stream>>>(col, rowStart, hnext, W2l, b2, W2r, flags, hcur,  n, e);
    k_gc3<<<ngc, 256, 0, stream>>>(col, rowStart, hcur,  W3l, b3, W3r, flags, h3,    n, e);

    // pool + softmax
    k_pool_softmax<<<NGRAPH, 64, 0, stream>>>(h3, bat, flags, d_out, n);
}

// Round 11
// 411.919 us; speedup vs baseline: 1.0653x; 1.0653x over previous
//
#include <hip/hip_runtime.h>
#include <hip/hip_bf16.h>

#define N_FEAT 128
#define HID 16
#define NCLS 10
#define NGRAPH 1024
#define SHIFT 7            // 128 nodes per coarse bin
#define NBMAX 1024         // supports n <= 131072
#define CAP 9216           // LDS staging entries in k_place (36 KB, +11 sigma)
#define CH 8192            // edges per binning block
#define EPB (CH / 256)     // edges per thread in k_binhist (256 thr)
#define EPB2 (CH / 512)    // edges per thread in k_binplace (512 thr)
#define GC_NODES 64        // nodes per gather block (4 threads/node, 256 thr)
#define GCAP2 5120         // LDS col staging in k_gc (20 KB, ~16 sigma at mean 4096)

__device__ __forceinline__ float u2f(unsigned int u) {
    union { unsigned int u; float f; } c; c.u = u; return c.f;
}
__device__ __forceinline__ float bf2f(__hip_bfloat16 b) {
    return __bfloat162float(b);
}
__device__ __forceinline__ unsigned short f2us(float f) {
    union { __hip_bfloat16 b; unsigned short u; } c;
    c.b = __float2bfloat16(f);
    return c.u;
}
__device__ __forceinline__ float ldw(const void* __restrict__ p, int i, int isbf) {
    return isbf ? bf2f(((const __hip_bfloat16*)p)[i]) : ((const float*)p)[i];
}
// unpack 8 bf16 packed in a uint4 into f[0..7]
__device__ __forceinline__ void unp8(uint4 v, float* f) {
    f[0] = u2f(v.x << 16); f[1] = u2f(v.x & 0xffff0000u);
    f[2] = u2f(v.y << 16); f[3] = u2f(v.y & 0xffff0000u);
    f[4] = u2f(v.z << 16); f[5] = u2f(v.z & 0xffff0000u);
    f[6] = u2f(v.w << 16); f[7] = u2f(v.w & 0xffff0000u);
}
// accumulate 8 bf16 packed in a uint4 into a8[0..7]
__device__ __forceinline__ void acc8(uint4 v, float* a8) {
    a8[0] += u2f(v.x << 16); a8[1] += u2f(v.x & 0xffff0000u);
    a8[2] += u2f(v.y << 16); a8[3] += u2f(v.y & 0xffff0000u);
    a8[4] += u2f(v.z << 16); a8[5] += u2f(v.z & 0xffff0000u);
    a8[6] += u2f(v.w << 16); a8[7] += u2f(v.w & 0xffff0000u);
}

// ---------------------------------------------------------------------------
// K0: runtime dtype probes.
__global__ void k_detect(const int* __restrict__ ei,
                         const unsigned int* __restrict__ xw,
                         int* __restrict__ flags) {
    if (blockIdx.x == 0 && threadIdx.x == 0) {
        int nz = 0;
        for (int i = 1; i < 256; i += 2) nz |= ei[i];
        flags[0] = (nz == 0) ? 1 : 0;
        int cnt = 0;
        for (int i = 0; i < 64; i++) {
            unsigned int ef = xw[i] & 0x7F80u;
            if (ef >= 0x3C00u && ef <= 0x4080u) cnt++;
        }
        flags[1] = (cnt >= 32) ? 1 : 0;
    }
}

// ---------------------------------------------------------------------------
// K1: h0[i] = emb[argmax(x[i,:])]. 2 nodes per wave, float4/uint2 loads
// (R9 win — kept).
__global__ void k_argmax_embed(const void* __restrict__ x,
                               const void* __restrict__ emb,
                               const int* __restrict__ flags,
                               unsigned short* __restrict__ h, int n) {
    int wave = (int)((blockIdx.x * (unsigned)blockDim.x + threadIdx.x) >> 6);
    int lane = threadIdx.x & 63;
    int half = lane >> 5;
    int l = lane & 31;
    int node = wave * 2 + half;
    if (node >= n) return;
    int isbf = flags[1];
    float v[4];
    if (isbf) {
        uint2 u = ((const uint2*)((const __hip_bfloat16*)x + (size_t)node * N_FEAT))[l];
        v[0] = u2f(u.x << 16); v[1] = u2f(u.x & 0xffff0000u);
        v[2] = u2f(u.y << 16); v[3] = u2f(u.y & 0xffff0000u);
    } else {
        float4 u = ((const float4*)((const float*)x + (size_t)node * N_FEAT))[l];
        v[0] = u.x; v[1] = u.y; v[2] = u.z; v[3] = u.w;
    }
    float bv = v[0]; int bi = 4 * l;
    #pragma unroll
    for (int k = 1; k < 4; k++)
        if (v[k] > bv) { bv = v[k]; bi = 4 * l + k; }
    #pragma unroll
    for (int off = 1; off < 32; off <<= 1) {
        float ov = __shfl_xor(bv, off);
        int   oi = __shfl_xor(bi, off);
        if (ov > bv || (ov == bv && oi < bi)) { bv = ov; bi = oi; }
    }
    if (l < HID) {
        unsigned short us;
        if (isbf) us = ((const unsigned short*)emb)[bi * HID + l];  // exact copy
        else      us = f2us(((const float*)emb)[bi * HID + l]);
        h[(size_t)node * HID + l] = us;
    }
}

// ---------------------------------------------------------------------------
// K2a: per-block LDS bin histogram -> plain coalesced store of the count row
// (R8 configuration — rbBuf rows; reverted from the cursor experiment).
__global__ void k_binhist(const int* __restrict__ ei, const int* __restrict__ flags,
                          int* __restrict__ rbBuf, int e, int nbins) {
    __shared__ int lh[NBMAX];
    int t = threadIdx.x;
    for (int b = t; b < nbins; b += 256) lh[b] = 0;
    __syncthreads();
    int base = blockIdx.x * CH;
    int sh = flags[0];
    for (int j = 0; j < EPB; j++) {
        int i = base + j * 256 + t;
        if (i < e) {
            int d = ei[((size_t)(e + i)) << sh];
            atomicAdd(&lh[d >> SHIFT], 1);
        }
    }
    __syncthreads();
    int* row = rbBuf + (size_t)blockIdx.x * nbins;
    for (int b = t; b < nbins; b += 256) row[b] = lh[b];
}

// K2b: per-bin exclusive scan over blocks (in place).
__global__ void k_colscan(int* __restrict__ rbBuf, int* __restrict__ binCnt,
                          int nblk, int nbins) {
    __shared__ int ls[1024];
    int b = blockIdx.x, t = threadIdx.x;
    int v = (t < nblk) ? rbBuf[(size_t)t * nbins + b] : 0;
    ls[t] = v;
    __syncthreads();
    #pragma unroll
    for (int off = 1; off < 1024; off <<= 1) {
        int w = (t >= off) ? ls[t - off] : 0;
        __syncthreads();
        ls[t] += w;
        __syncthreads();
    }
    if (t < nblk) rbBuf[(size_t)t * nbins + b] = ls[t] - v;
    if (t == 1023) binCnt[b] = ls[t];
}

// K2c: exclusive scan of binCnt -> binStart.
__global__ void k_scanbins(const int* __restrict__ binCnt,
                           int* __restrict__ binStart, int nbins, int e) {
    __shared__ int ls[1024];
    int t = threadIdx.x;
    int v = (t < nbins) ? binCnt[t] : 0;
    ls[t] = v;
    __syncthreads();
    #pragma unroll
    for (int off = 1; off < 1024; off <<= 1) {
        int w = (t >= off) ? ls[t - off] : 0;
        __syncthreads();
        ls[t] += w;
        __syncthreads();
    }
    if (t < nbins) binStart[t] = ls[t] - v;
    if (t == 0) binStart[nbins] = e;
}

// K2d: coarse placement, LDS-sorted for coalesced writes (R8: 512 threads,
// rbBuf per-block bases — best measured config).
__global__ __launch_bounds__(512) void k_binplace(
        const int* __restrict__ ei, const int* __restrict__ flags,
        const int* __restrict__ binStart, const int* __restrict__ rbBuf,
        int* __restrict__ col, int e, int nbins) {
    __shared__ int cnt[NBMAX];
    __shared__ int ldsOff[NBMAX];
    __shared__ int ldsBase[NBMAX];
    __shared__ int ps[512];
    __shared__ int stage[CH];
    __shared__ unsigned short binOf[CH];
    int t = threadIdx.x;
    for (int b = t; b < nbins; b += 512) cnt[b] = 0;
    __syncthreads();
    int base = blockIdx.x * CH;
    int sh = flags[0];
    int myV[EPB2]; short myB[EPB2];
    for (int j = 0; j < EPB2; j++) {
        int i = base + j * 512 + t;
        if (i < e) {
            int s = ei[((size_t)i) << sh];
            int d = ei[((size_t)(e + i)) << sh];
            myV[j] = (s << SHIFT) | (d & ((1 << SHIFT) - 1));
            int b2 = d >> SHIFT;
            myB[j] = (short)b2;
            atomicAdd(&cnt[b2], 1);
        } else myB[j] = -1;
    }
    __syncthreads();
    int c[2]; int lsum = 0;
    int bb = t * 2;
    #pragma unroll
    for (int k = 0; k < 2; k++) {
        int b2 = bb + k;
        c[k] = (b2 < nbins) ? cnt[b2] : 0;
        lsum += c[k];
    }
    ps[t] = lsum;
    __syncthreads();
    #pragma unroll
    for (int off = 1; off < 512; off <<= 1) {
        int w = (t >= off) ? ps[t - off] : 0;
        __syncthreads();
        ps[t] += w;
        __syncthreads();
    }
    int run = ps[t] - lsum;
    #pragma unroll
    for (int k = 0; k < 2; k++) {
        int b2 = bb + k;
        if (b2 < nbins) ldsOff[b2] = run;
        run += c[k];
    }
    __syncthreads();
    const int* rb = rbBuf + (size_t)blockIdx.x * nbins;
    for (int b2 = t; b2 < nbins; b2 += 512) {
        ldsBase[b2] = binStart[b2] + rb[b2] - ldsOff[b2];
        cnt[b2] = 0;
    }
    __syncthreads();
    for (int j = 0; j < EPB2; j++) {
        if (myB[j] >= 0) {
            int b2 = myB[j];
            int r = atomicAdd(&cnt[b2], 1);
            int p = ldsOff[b2] + r;
            stage[p] = myV[j];
            binOf[p] = (unsigned short)b2;
        }
    }
    __syncthreads();
    int total = e - base;
    if (total > CH) total = CH;
    for (int i = t; i < total; i += 512) {
        int b2 = binOf[i];
        col[ldsBase[b2] + i] = stage[i];
    }
}

// K2e: fine placement + per-node rowStart (36 KB stage, 512 thr — R2/R6 win).
__global__ __launch_bounds__(512) void k_place(
        int* __restrict__ col, const int* __restrict__ binStart,
        int* __restrict__ rowStart, int n, int e) {
    __shared__ int stage[CAP];
    __shared__ int cntN[1 << SHIFT];
    __shared__ int sc[1 << SHIFT];
    __shared__ int rs[1 << SHIFT];
    int b = blockIdx.x;
    int t = threadIdx.x;
    int nb = b << SHIFT;
    int s0 = binStart[b];
    int s1 = binStart[b + 1];
    int cnt = s1 - s0;
    if (t < (1 << SHIFT)) cntN[t] = 0;
    bool st = (cnt <= CAP);
    __syncthreads();
    for (int i = t; i < cnt; i += 512) {
        int v = col[s0 + i];
        if (st) stage[i] = v;
        atomicAdd(&cntN[v & ((1 << SHIFT) - 1)], 1);
    }
    __syncthreads();
    if (t < (1 << SHIFT)) sc[t] = cntN[t];
    __syncthreads();
    #pragma unroll
    for (int off = 1; off < (1 << SHIFT); off <<= 1) {
        int w = 0;
        if (t < (1 << SHIFT) && t >= off) w = sc[t - off];
        __syncthreads();
        if (t < (1 << SHIFT)) sc[t] += w;
        __syncthreads();
    }
    if (t < (1 << SHIFT)) {
        int start = s0 + sc[t] - cntN[t];
        rs[t] = start;
        int node = nb + t;
        if (node < n) rowStart[node] = start;
        cntN[t] = 0;
    }
    __syncthreads();
    for (int i = t; i < cnt; i += 512) {
        int v = st ? stage[i] : col[s0 + i];
        int dl = v & ((1 << SHIFT) - 1);
        int r = atomicAdd(&cntN[dl], 1);
        col[rs[dl] + r] = v >> SHIFT;
    }
}

// ---------------------------------------------------------------------------
// K3: gather+combine, layers 1/2. R7 structure (FROZEN — MSHR-bound floor).
__global__ __launch_bounds__(256) void k_gc(
        const int* __restrict__ col, const int* __restrict__ rowStart,
        const unsigned short* __restrict__ hin,
        const void* __restrict__ Wl, const void* __restrict__ bia,
        const void* __restrict__ Wr, const int* __restrict__ flags,
        unsigned short* __restrict__ hout, int n, int e) {
    __shared__ int ecol[GCAP2];
    __shared__ float wl[HID][HID], wr[HID][HID], bb[HID];
    int t = threadIdx.x;
    int b = blockIdx.x;
    int isbf = flags[1];
    if (t < HID * HID) {
        wl[t >> 4][t & 15] = ldw(Wl, t, isbf);
        wr[t >> 4][t & 15] = ldw(Wr, t, isbf);
    }
    if (t < HID) bb[t] = ldw(bia, t, isbf);
    int nb = b * GC_NODES;
    int s0 = rowStart[nb];
    int s1 = (nb + GC_NODES < n) ? rowStart[nb + GC_NODES] : e;
    int nl = t >> 2;                      // node-local 0..63
    int q  = t & 3;                       // edge-quarter
    int node = nb + nl;
    bool act = (node < n);
    int lo = 0, hi = 0;
    if (act) {
        lo = rowStart[node];
        hi = (node + 1 < n) ? rowStart[node + 1] : e;
    }
    const uint4* h4 = (const uint4*)hin;
    uint4 sv0, sv1;
    if (act && q == 0) {                  // hoist self-row ahead of staging
        sv0 = h4[(size_t)node * 2];
        sv1 = h4[(size_t)node * 2 + 1];
    }
    int cnt = s1 - s0;
    bool st = (cnt <= GCAP2);
    if (st)
        for (int i = t; i < cnt; i += 256)
            ecol[i] = __builtin_nontemporal_load(col + s0 + i);
    __syncthreads();
    if (!act) return;

    float a16[16];
    #pragma unroll
    for (int k = 0; k < 16; k++) a16[k] = 0.0f;
    if (st) {
        int i = lo - s0 + q;
        int end = hi - s0;
        for (; i + 12 < end; i += 16) {
            int e0 = ecol[i], e1 = ecol[i + 4], e2 = ecol[i + 8], e3 = ecol[i + 12];
            uint4 va0 = h4[(size_t)e0 * 2],     vb0 = h4[(size_t)e0 * 2 + 1];
            uint4 va1 = h4[(size_t)e1 * 2],     vb1 = h4[(size_t)e1 * 2 + 1];
            uint4 va2 = h4[(size_t)e2 * 2],     vb2 = h4[(size_t)e2 * 2 + 1];
            uint4 va3 = h4[(size_t)e3 * 2],     vb3 = h4[(size_t)e3 * 2 + 1];
            acc8(va0, a16); acc8(vb0, a16 + 8);
            acc8(va1, a16); acc8(vb1, a16 + 8);
            acc8(va2, a16); acc8(vb2, a16 + 8);
            acc8(va3, a16); acc8(vb3, a16 + 8);
        }
        for (; i < end; i += 4) {
            int s = ecol[i];
            uint4 va = h4[(size_t)s * 2], vb = h4[(size_t)s * 2 + 1];
            acc8(va, a16); acc8(vb, a16 + 8);
        }
    } else {
        int i = lo + q;
        for (; i + 12 < hi; i += 16) {
            int e0 = col[i], e1 = col[i + 4], e2 = col[i + 8], e3 = col[i + 12];
            uint4 va0 = h4[(size_t)e0 * 2],     vb0 = h4[(size_t)e0 * 2 + 1];
            uint4 va1 = h4[(size_t)e1 * 2],     vb1 = h4[(size_t)e1 * 2 + 1];
            uint4 va2 = h4[(size_t)e2 * 2],     vb2 = h4[(size_t)e2 * 2 + 1];
            uint4 va3 = h4[(size_t)e3 * 2],     vb3 = h4[(size_t)e3 * 2 + 1];
            acc8(va0, a16); acc8(vb0, a16 + 8);
            acc8(va1, a16); acc8(vb1, a16 + 8);
            acc8(va2, a16); acc8(vb2, a16 + 8);
            acc8(va3, a16); acc8(vb3, a16 + 8);
        }
        for (; i < hi; i += 4) {
            int s = col[i];
            uint4 va = h4[(size_t)s * 2], vb = h4[(size_t)s * 2 + 1];
            acc8(va, a16); acc8(vb, a16 + 8);
        }
    }
    // q-reduction (q occupies lane bits 0-1)
    #pragma unroll
    for (int k = 0; k < 16; k++) a16[k] += __shfl_xor(a16[k], 1);
    #pragma unroll
    for (int k = 0; k < 16; k++) a16[k] += __shfl_xor(a16[k], 2);
    if (q == 0) {
        float invd = 1.0f / fmaxf((float)(hi - lo), 1.0f);
        #pragma unroll
        for (int k = 0; k < 16; k++) a16[k] *= invd;
        float hb[HID];
        unp8(sv0, hb);
        unp8(sv1, hb + 8);
        float o[HID]; float sq = 0.0f;
        #pragma unroll
        for (int f = 0; f < HID; f++) {
            float acc = bb[f];
            #pragma unroll
            for (int k = 0; k < HID; k++)
                acc += a16[k] * wl[f][k] + hb[k] * wr[f][k];
            o[f] = acc;
            sq += acc * acc;
        }
        float inn = 1.0f / fmaxf(sqrtf(sq), 1e-12f);
        uint4 w0, w1;
        unsigned int* wp0 = (unsigned int*)&w0;
        unsigned int* wp1 = (unsigned int*)&w1;
        #pragma unroll
        for (int v = 0; v < 4; v++) {
            unsigned int l0 = f2us(fmaxf(o[2 * v] * inn, 0.0f));
            unsigned int h0 = f2us(fmaxf(o[2 * v + 1] * inn, 0.0f));
            wp0[v] = l0 | (h0 << 16);
            unsigned int l1 = f2us(fmaxf(o[8 + 2 * v] * inn, 0.0f));
            unsigned int h1 = f2us(fmaxf(o[8 + 2 * v + 1] * inn, 0.0f));
            wp1[v] = l1 | (h1 << 16);
        }
        ((uint4*)hout)[(size_t)node * 2]     = w0;
        ((uint4*)hout)[(size_t)node * 2 + 1] = w1;
    }
}

// K4: same structure, layer 3 (10 outputs, no ReLU, fp32 h3). FROZEN.
__global__ __launch_bounds__(256) void k_gc3(
        const int* __restrict__ col, const int* __restrict__ rowStart,
        const unsigned short* __restrict__ hin,
        const void* __restrict__ Wl, const void* __restrict__ bia,
        const void* __restrict__ Wr, const int* __restrict__ flags,
        float* __restrict__ h3, int n, int e) {
    __shared__ int ecol[GCAP2];
    __shared__ float wl[NCLS][HID], wr[NCLS][HID], bb[NCLS];
    int t = threadIdx.x;
    int b = blockIdx.x;
    int isbf = flags[1];
    if (t < NCLS * HID) {
        wl[t >> 4][t & 15] = ldw(Wl, t, isbf);
        wr[t >> 4][t & 15] = ldw(Wr, t, isbf);
    }
    if (t < NCLS) bb[t] = ldw(bia, t, isbf);
    int nb = b * GC_NODES;
    int s0 = rowStart[nb];
    int s1 = (nb + GC_NODES < n) ? rowStart[nb + GC_NODES] : e;
    int nl = t >> 2;
    int q  = t & 3;
    int node = nb + nl;
    bool act = (node < n);
    int lo = 0, hi = 0;
    if (act) {
        lo = rowStart[node];
        hi = (node + 1 < n) ? rowStart[node + 1] : e;
    }
    const uint4* h4 = (const uint4*)hin;
    uint4 sv0, sv1;
    if (act && q == 0) {
        sv0 = h4[(size_t)node * 2];
        sv1 = h4[(size_t)node * 2 + 1];
    }
    int cnt = s1 - s0;
    bool st = (cnt <= GCAP2);
    if (st)
        for (int i = t; i < cnt; i += 256)
            ecol[i] = __builtin_nontemporal_load(col + s0 + i);
    __syncthreads();
    if (!act) return;

    float a16[16];
    #pragma unroll
    for (int k = 0; k < 16; k++) a16[k] = 0.0f;
    if (st) {
        int i = lo - s0 + q;
        int end = hi - s0;
        for (; i + 12 < end; i += 16) {
            int e0 = ecol[i], e1 = ecol[i + 4], e2 = ecol[i + 8], e3 = ecol[i + 12];
            uint4 va0 = h4[(size_t)e0 * 2],     vb0 = h4[(size_t)e0 * 2 + 1];
            uint4 va1 = h4[(size_t)e1 * 2],     vb1 = h4[(size_t)e1 * 2 + 1];
            uint4 va2 = h4[(size_t)e2 * 2],     vb2 = h4[(size_t)e2 * 2 + 1];
            uint4 va3 = h4[(size_t)e3 * 2],     vb3 = h4[(size_t)e3 * 2 + 1];
            acc8(va0, a16); acc8(vb0, a16 + 8);
            acc8(va1, a16); acc8(vb1, a16 + 8);
            acc8(va2, a16); acc8(vb2, a16 + 8);
            acc8(va3, a16); acc8(vb3, a16 + 8);
        }
        for (; i < end; i += 4) {
            int s = ecol[i];
            uint4 va = h4[(size_t)s * 2], vb = h4[(size_t)s * 2 + 1];
            acc8(va, a16); acc8(vb, a16 + 8);
        }
    } else {
        int i = lo + q;
        for (; i + 12 < hi; i += 16) {
            int e0 = col[i], e1 = col[i + 4], e2 = col[i + 8], e3 = col[i + 12];
            uint4 va0 = h4[(size_t)e0 * 2],     vb0 = h4[(size_t)e0 * 2 + 1];
            uint4 va1 = h4[(size_t)e1 * 2],     vb1 = h4[(size_t)e1 * 2 + 1];
            uint4 va2 = h4[(size_t)e2 * 2],     vb2 = h4[(size_t)e2 * 2 + 1];
            uint4 va3 = h4[(size_t)e3 * 2],     vb3 = h4[(size_t)e3 * 2 + 1];
            acc8(va0, a16); acc8(vb0, a16 + 8);
            acc8(va1, a16); acc8(vb1, a16 + 8);
            acc8(va2, a16); acc8(vb2, a16 + 8);
            acc8(va3, a16); acc8(vb3, a16 + 8);
        }
        for (; i < hi; i += 4) {
            int s = col[i];
            uint4 va = h4[(size_t)s * 2], vb = h4[(size_t)s * 2 + 1];
            acc8(va, a16); acc8(vb, a16 + 8);
        }
    }
    #pragma unroll
    for (int k = 0; k < 16; k++) a16[k] += __shfl_xor(a16[k], 1);
    #pragma unroll
    for (int k = 0; k < 16; k++) a16[k] += __shfl_xor(a16[k], 2);
    if (q == 0) {
        float invd = 1.0f / fmaxf((float)(hi - lo), 1.0f);
        #pragma unroll
        for (int k = 0; k < 16; k++) a16[k] *= invd;
        float hb[HID];
        unp8(sv0, hb);
        unp8(sv1, hb + 8);
        float o[NCLS]; float sq = 0.0f;
        #pragma unroll
        for (int f = 0; f < NCLS; f++) {
            float acc = bb[f];
            #pragma unroll
            for (int k = 0; k < HID; k++)
                acc += a16[k] * wl[f][k] + hb[k] * wr[f][k];
            o[f] = acc;
            sq += acc * acc;
        }
        float inn = 1.0f / fmaxf(sqrtf(sq), 1e-12f);
        float* op = h3 + (size_t)node * NCLS;
        #pragma unroll
        for (int f = 0; f < NCLS; f++) op[f] = o[f] * inn;
    }
}

// ---------------------------------------------------------------------------
// K5: per-graph mean pool (batch sorted -> binary search) + softmax.
__device__ __forceinline__ int lbound(const int* __restrict__ a, int n, int key, int sh) {
    int lo = 0, hi = n;
    while (lo < hi) {
        int mid = (lo + hi) >> 1;
        if (a[((size_t)mid) << sh] < key) lo = mid + 1; else hi = mid;
    }
    return lo;
}

__global__ void k_pool_softmax(const float* __restrict__ h3,
                               const int* __restrict__ batch,
                               const int* __restrict__ flags,
                               void* __restrict__ out, int n) {
    int g = blockIdx.x;
    int lane = threadIdx.x;
    int sh = flags[0];
    int lo = lbound(batch, n, g, sh);
    int hi = lbound(batch, n, g + 1, sh);
    float acc[NCLS];
    #pragma unroll
    for (int c = 0; c < NCLS; c++) acc[c] = 0.0f;
    for (int i = lo + lane; i < hi; i += 64) {
        const float* r = h3 + (size_t)i * NCLS;
        #pragma unroll
        for (int c = 0; c < NCLS; c++) acc[c] += r[c];
    }
    #pragma unroll
    for (int c = 0; c < NCLS; c++) {
        #pragma unroll
        for (int off = 1; off < 64; off <<= 1)
            acc[c] += __shfl_xor(acc[c], off);
    }
    float invc = 1.0f / fmaxf((float)(hi - lo), 1.0f);
    float m = -1e30f;
    #pragma unroll
    for (int c = 0; c < NCLS; c++) { acc[c] *= invc; m = fmaxf(m, acc[c]); }
    float s = 0.0f;
    #pragma unroll
    for (int c = 0; c < NCLS; c++) { acc[c] = expf(acc[c] - m); s += acc[c]; }
    float invs = 1.0f / s;
    if (lane < NCLS) {
        float v = acc[lane] * invs;
        size_t idx = (size_t)g * NCLS + lane;
        if (flags[1]) ((__hip_bfloat16*)out)[idx] = __float2bfloat16(v);
        else          ((float*)out)[idx] = v;
    }
}

// ---------------------------------------------------------------------------
extern "C" void kernel_launch(void* const* d_in, const int* in_sizes, int n_in,
                              void* d_out, int out_size, void* d_ws, size_t ws_size,
                              hipStream_t stream) {
    const void* x   = d_in[0];
    const int*  ei  = (const int*)d_in[1];
    const int*  bat = (const int*)d_in[2];
    const void* emb = d_in[3];
    const void* W1l = d_in[4];  const void* b1 = d_in[5];  const void* W1r = d_in[6];
    const void* W2l = d_in[7];  const void* b2 = d_in[8];  const void* W2r = d_in[9];
    const void* W3l = d_in[10]; const void* b3 = d_in[11]; const void* W3r = d_in[12];

    int n = in_sizes[0] / N_FEAT;
    int e = in_sizes[1] / 2;
    int nbins = (n + (1 << SHIFT) - 1) >> SHIFT;
    int nblk  = (e + CH - 1) / CH;

    // ws: hcur[16n] bf16 | hnext[16n] bf16 | h3[10n] f32 | col[e] |
    //     rowStart[n] | binCnt | binStart | rbBuf[nblk*nbins] | flags
    unsigned short* hcur  = (unsigned short*)d_ws;
    unsigned short* hnext = hcur + (size_t)n * HID;
    float* h3       = (float*)(hnext + (size_t)n * HID);
    int*   col      = (int*)(h3 + (size_t)n * NCLS);
    int*   rowStart = col + e;
    int*   binCnt   = rowStart + n;
    int*   binStart = binCnt + nbins;
    int*   rbBuf    = binStart + (nbins + 1);
    int*   flags    = rbBuf + (size_t)nblk * nbins;

    int ngridA = (n + 7) / 8;   // argmax: 2 nodes/wave, 4 waves/block
    int ngc = (n + GC_NODES - 1) / GC_NODES;

    // probes + CSR build (R8 configuration — best measured)
    k_detect<<<1, 64, 0, stream>>>(ei, (const unsigned int*)x, flags);
    k_binhist<<<nblk, 256, 0, stream>>>(ei, flags, rbBuf, e, nbins);
    k_colscan<<<nbins, 1024, 0, stream>>>(rbBuf, binCnt, nblk, nbins);
    k_scanbins<<<1, 1024, 0, stream>>>(binCnt, binStart, nbins, e);
    k_binplace<<<nblk, 512, 0, stream>>>(ei, flags, binStart, rbBuf, col, e, nbins);
    k_place<<<nbins, 512, 0, stream>>>(col, binStart, rowStart, n, e);

    // initial embedding (bf16 h table)
    k_argmax_embed<<<ngridA, 256, 0, stream>>>(x, emb, flags, hcur, n);

    // 3 gather+combine layers (64-node blocks, LDS-staged col, full-row loads)
    k_gc <<<ngc, 256, 0, stream>>>(col, rowStart, hcur,  W1l, b1, W1r, flags, hnext, n, e);
    k_gc <<<ngc, 256, 0, stream>>>(col, rowStart, hnext, W2l, b2, W2r, flags, hcur,  n, e);
    k_gc3<<<ngc, 256, 0, stream>>>(col, rowStart, hcur,  W3l, b3, W3r, flags, h3,    n, e);

    // pool + softmax
    k_pool_softmax<<<NGRAPH, 64, 0, stream>>>(h3, bat, flags, d_out, n);
}